// Round 5
// baseline (680.896 us; speedup 1.0000x reference)
//
#include <hip/hip_runtime.h>
#include <hip/hip_bf16.h>

#define NN   4096
#define HID  128
#define INFE 64
#define KMAX 192   // max edges/row: Binomial(4096,0.02) max ~122 across 4096 rows; 192 safe
#define CH   64    // edges per chunk
#define RPB  4     // rows per block in k_step

typedef unsigned short u16;

__device__ __forceinline__ float bfu(u16 u) { return __uint_as_float(((unsigned)u) << 16); }
__device__ __forceinline__ u16 f2b(float f) { __hip_bfloat16 h = __float2bfloat16(f); return *(u16*)&h; }

// ---- h0 = x @ W_in + b_in : one block (128 thr) per row; DB: store bf16 else fp32 ----
template<bool DB>
__global__ __launch_bounds__(128) void k_h0(
    const float* __restrict__ x, const float* __restrict__ Win, const float* __restrict__ bin,
    void* __restrict__ hdst)
{
    __shared__ float xl[INFE];
    const int r = blockIdx.x;
    const int d = threadIdx.x;
    if (d < INFE) xl[d] = x[(size_t)r*INFE + d];
    __syncthreads();
    float acc = bin[d];
    #pragma unroll 8
    for (int k = 0; k < INFE; ++k)
        acc = fmaf(xl[k], Win[k*HID + d], acc);
    if (DB) ((u16*)hdst)[(size_t)r*HID + d] = f2b(acc);
    else    ((float*)hdst)[(size_t)r*HID + d] = acc;
}

// ---- fused step: edge-compact + message + MLP + residual + LayerNorm ----
// One 128-thr block handles RPB=4 rows. SB/DB: h src/dst stored bf16 (true) or fp32.
template<bool SB, bool DB>
__global__ __launch_bounds__(128) void k_step(
    const float* __restrict__ adj, const float* __restrict__ dist,
    const void* hsrc, void* hdst,
    const float* __restrict__ Wu1, const float* __restrict__ bu1,
    const float* __restrict__ Wu2, const float* __restrict__ bu2,
    const float* __restrict__ gam, const float* __restrict__ bet)
{
    __shared__ int   cnt4[RPB];
    __shared__ int   cl[RPB][KMAX];
    __shared__ float w1l[RPB][KMAX], w2l[RPB][KMAX];
    __shared__ __align__(16) float hs4[RPB][HID];   // this block's src rows (fp32)
    __shared__ __align__(16) float hj[CH][HID + 1]; // gathered neighbor rows
    __shared__ float pl[CH];
    __shared__ __align__(16) float ms[RPB][HID];    // messages
    __shared__ __align__(16) float h1s[RPB][HID];   // MLP hidden
    __shared__ float hn[RPB][HID];                  // pre-LN
    const int r0 = blockIdx.x * RPB;
    const int t  = threadIdx.x;
    const u16*   s16 = (const u16*)hsrc;
    const float* s32 = (const float*)hsrc;

    if (t < RPB) cnt4[t] = 0;
    for (int i = t; i < RPB*HID; i += 128) {
        int rr = i >> 7, d = i & 127;
        hs4[rr][d] = SB ? bfu(s16[(size_t)(r0+rr)*HID + d]) : s32[(size_t)(r0+rr)*HID + d];
    }
    __syncthreads();

    // phase 1: scan 4 adjacency rows (float4), fold distance terms, compact into LDS
    for (int idx = t; idx < RPB*(NN/4); idx += 128) {
        int rr = idx >> 10;          // NN/4 = 1024 float4 per row
        int c4 = idx & 1023;
        float4 a4 = ((const float4*)(adj + (size_t)(r0+rr)*NN))[c4];
        if (a4.x != 0.f || a4.y != 0.f || a4.z != 0.f || a4.w != 0.f) {
            const float* drow = dist + (size_t)(r0+rr)*NN;
            float av4[4] = {a4.x, a4.y, a4.z, a4.w};
            #pragma unroll
            for (int q = 0; q < 4; ++q) {
                float av = av4[q];
                if (av != 0.f) {
                    int c = 4*c4 + q;
                    float d  = fmaxf(drow[c], 1e-6f);
                    float dw1 = av * __expf(-d * (1.0f/3.0f));
                    float tt = 3.5f / d;
                    float t2 = tt*tt;
                    float t6 = t2*t2*t2;
                    float dw2 = av * 0.04f * (t6*t6 - t6);   // 0.1 * 4*eps*(sr12-sr6)
                    int pos = atomicAdd(&cnt4[rr], 1);
                    if (pos < KMAX) { cl[rr][pos] = c; w1l[rr][pos] = dw1; w2l[rr][pos] = dw2; }
                }
            }
        }
    }
    __syncthreads();
    int npv[RPB];
    for (int rr = 0; rr < RPB; ++rr) {
        int n  = cnt4[rr] < KMAX ? cnt4[rr] : KMAX;
        int np = (n + CH - 1) / CH * CH;                     // pad with null edges (w=0)
        npv[rr] = np;
        for (int i = n + t; i < np; i += 128) { cl[rr][i] = 0; w1l[rr][i] = 0.f; w2l[rr][i] = 0.f; }
    }
    __syncthreads();

    // phase 2: per row, 64-edge chunks: gather h_j, dot, weight, accumulate
    const int e2 = t >> 1;   // edge within chunk (2 threads/edge)
    const int hf = t & 1;    // 64-dim half
    for (int rr = 0; rr < RPB; ++rr) {
        float acc = 0.f;
        for (int e0 = 0; e0 < npv[rr]; e0 += CH) {
            int c = cl[rr][e0 + e2];
            float* dst = &hj[e2][hf*64];
            if (SB) {
                const uint4* sv = (const uint4*)(s16 + (size_t)c*HID + hf*64);
                #pragma unroll
                for (int i = 0; i < 8; ++i) {
                    uint4 v = sv[i];
                    dst[8*i+0] = __uint_as_float(v.x << 16); dst[8*i+1] = __uint_as_float(v.x & 0xffff0000u);
                    dst[8*i+2] = __uint_as_float(v.y << 16); dst[8*i+3] = __uint_as_float(v.y & 0xffff0000u);
                    dst[8*i+4] = __uint_as_float(v.z << 16); dst[8*i+5] = __uint_as_float(v.z & 0xffff0000u);
                    dst[8*i+6] = __uint_as_float(v.w << 16); dst[8*i+7] = __uint_as_float(v.w & 0xffff0000u);
                }
            } else {
                const float4* sv = (const float4*)(s32 + (size_t)c*HID + hf*64);
                #pragma unroll
                for (int i = 0; i < 16; ++i) {
                    float4 v = sv[i];
                    dst[4*i+0] = v.x; dst[4*i+1] = v.y; dst[4*i+2] = v.z; dst[4*i+3] = v.w;
                }
            }
            __syncthreads();
            {
                const float* ha = &hs4[rr][hf*64];
                const float* hb = &hj[e2][hf*64];
                float p = 0.f;
                #pragma unroll
                for (int i = 0; i < 64; ++i) p = fmaf(ha[i], hb[i], p);
                p += __shfl_xor(p, 1);
                if (hf == 0) {
                    int e = e0 + e2;
                    pl[e2] = fmaf(w1l[rr][e], fmaxf(p, 0.f), w2l[rr][e]);
                }
            }
            __syncthreads();
            #pragma unroll
            for (int i = 0; i < CH; ++i)
                acc = fmaf(pl[i], hj[i][t], acc);
            __syncthreads();
        }
        ms[rr][t] = acc;
    }
    __syncthreads();

    // phase A: h1 = relu([h, m] @ W_u1 + b_u1)
    {
        float bb = bu1[t];
        float a0 = bb, a1 = bb, a2 = bb, a3 = bb;
        for (int k = 0; k < HID; k += 4) {   // h part
            float w0 = Wu1[(k+0)*HID + t];
            float w1 = Wu1[(k+1)*HID + t];
            float w2 = Wu1[(k+2)*HID + t];
            float w3 = Wu1[(k+3)*HID + t];
            float4 c0 = *(const float4*)&hs4[0][k];
            float4 c1 = *(const float4*)&hs4[1][k];
            float4 c2 = *(const float4*)&hs4[2][k];
            float4 c3 = *(const float4*)&hs4[3][k];
            a0 = fmaf(c0.x,w0,a0); a0 = fmaf(c0.y,w1,a0); a0 = fmaf(c0.z,w2,a0); a0 = fmaf(c0.w,w3,a0);
            a1 = fmaf(c1.x,w0,a1); a1 = fmaf(c1.y,w1,a1); a1 = fmaf(c1.z,w2,a1); a1 = fmaf(c1.w,w3,a1);
            a2 = fmaf(c2.x,w0,a2); a2 = fmaf(c2.y,w1,a2); a2 = fmaf(c2.z,w2,a2); a2 = fmaf(c2.w,w3,a2);
            a3 = fmaf(c3.x,w0,a3); a3 = fmaf(c3.y,w1,a3); a3 = fmaf(c3.z,w2,a3); a3 = fmaf(c3.w,w3,a3);
        }
        for (int k = 0; k < HID; k += 4) {   // m part (rows 128..255 of Wu1)
            float w0 = Wu1[(HID+k+0)*HID + t];
            float w1 = Wu1[(HID+k+1)*HID + t];
            float w2 = Wu1[(HID+k+2)*HID + t];
            float w3 = Wu1[(HID+k+3)*HID + t];
            float4 c0 = *(const float4*)&ms[0][k];
            float4 c1 = *(const float4*)&ms[1][k];
            float4 c2 = *(const float4*)&ms[2][k];
            float4 c3 = *(const float4*)&ms[3][k];
            a0 = fmaf(c0.x,w0,a0); a0 = fmaf(c0.y,w1,a0); a0 = fmaf(c0.z,w2,a0); a0 = fmaf(c0.w,w3,a0);
            a1 = fmaf(c1.x,w0,a1); a1 = fmaf(c1.y,w1,a1); a1 = fmaf(c1.z,w2,a1); a1 = fmaf(c1.w,w3,a1);
            a2 = fmaf(c2.x,w0,a2); a2 = fmaf(c2.y,w1,a2); a2 = fmaf(c2.z,w2,a2); a2 = fmaf(c2.w,w3,a2);
            a3 = fmaf(c3.x,w0,a3); a3 = fmaf(c3.y,w1,a3); a3 = fmaf(c3.z,w2,a3); a3 = fmaf(c3.w,w3,a3);
        }
        h1s[0][t] = fmaxf(a0, 0.f); h1s[1][t] = fmaxf(a1, 0.f);
        h1s[2][t] = fmaxf(a2, 0.f); h1s[3][t] = fmaxf(a3, 0.f);
    }
    __syncthreads();
    // phase B: delta = h1 @ W_u2 + b_u2 ; hn = h + delta
    {
        float bb = bu2[t];
        float b0 = bb, b1 = bb, b2 = bb, b3 = bb;
        for (int k = 0; k < HID; k += 4) {
            float w0 = Wu2[(k+0)*HID + t];
            float w1 = Wu2[(k+1)*HID + t];
            float w2 = Wu2[(k+2)*HID + t];
            float w3 = Wu2[(k+3)*HID + t];
            float4 c0 = *(const float4*)&h1s[0][k];
            float4 c1 = *(const float4*)&h1s[1][k];
            float4 c2 = *(const float4*)&h1s[2][k];
            float4 c3 = *(const float4*)&h1s[3][k];
            b0 = fmaf(c0.x,w0,b0); b0 = fmaf(c0.y,w1,b0); b0 = fmaf(c0.z,w2,b0); b0 = fmaf(c0.w,w3,b0);
            b1 = fmaf(c1.x,w0,b1); b1 = fmaf(c1.y,w1,b1); b1 = fmaf(c1.z,w2,b1); b1 = fmaf(c1.w,w3,b1);
            b2 = fmaf(c2.x,w0,b2); b2 = fmaf(c2.y,w1,b2); b2 = fmaf(c2.z,w2,b2); b2 = fmaf(c2.w,w3,b2);
            b3 = fmaf(c3.x,w0,b3); b3 = fmaf(c3.y,w1,b3); b3 = fmaf(c3.z,w2,b3); b3 = fmaf(c3.w,w3,b3);
        }
        hn[0][t] = hs4[0][t] + b0;
        hn[1][t] = hs4[1][t] + b1;
        hn[2][t] = hs4[2][t] + b2;
        hn[3][t] = hs4[3][t] + b3;
    }
    __syncthreads();
    // LayerNorm: 32 lanes per row (xor masks <32 stay in-group), then store dst
    {
        const int lr = t >> 5;
        const int j  = t & 31;
        float s = 0.f;
        #pragma unroll
        for (int q = 0; q < 4; ++q) s += hn[lr][j + 32*q];
        #pragma unroll
        for (int k2 = 16; k2 >= 1; k2 >>= 1) s += __shfl_xor(s, k2);
        float mu = s * (1.0f/128.0f);
        float v = 0.f;
        #pragma unroll
        for (int q = 0; q < 4; ++q) { float z = hn[lr][j + 32*q] - mu; v = fmaf(z, z, v); }
        #pragma unroll
        for (int k2 = 16; k2 >= 1; k2 >>= 1) v += __shfl_xor(v, k2);
        float rstd = rsqrtf(v * (1.0f/128.0f) + 1e-5f);
        #pragma unroll
        for (int q = 0; q < 4; ++q) {
            int dd = j + 32*q;
            float val = fmaf((hn[lr][dd] - mu) * rstd, gam[dd], bet[dd]);
            if (DB) ((u16*)hdst)[(size_t)(r0+lr)*HID + dd] = f2b(val);
            else    ((float*)hdst)[(size_t)(r0+lr)*HID + dd] = val;
        }
    }
}

extern "C" void kernel_launch(void* const* d_in, const int* in_sizes, int n_in,
                              void* d_out, int out_size, void* d_ws, size_t ws_size,
                              hipStream_t stream)
{
    // Inputs fp32 (proven: fp32-as-bf16 parse NaN'd via dist denormal -> 1e-6 clamp -> inf).
    // Output fp32: reference returns jnp.float32 -> d_out is float*.
    const float* x    = (const float*)d_in[0];
    const float* adj  = (const float*)d_in[1];
    const float* dist = (const float*)d_in[2];
    const float* Win  = (const float*)d_in[3];
    const float* bin  = (const float*)d_in[4];
    // d_in[5] W_msg, d_in[6] b_msg: dead code in reference
    const float* Wu1  = (const float*)d_in[7];
    const float* bu1  = (const float*)d_in[8];
    const float* Wu2  = (const float*)d_in[9];
    const float* bu2  = (const float*)d_in[10];
    const float* gam  = (const float*)d_in[11];
    const float* bet  = (const float*)d_in[12];

    const size_t hb32 = (size_t)NN * HID * sizeof(float);   // 2 MB fp32 h buffer
    if (ws_size >= 2 * hb32) {
        // Path A: fp32 h double-buffer in ws; final fp32 -> d_out
        void* A = d_ws;
        void* B = (char*)d_ws + hb32;
        k_h0<false><<<NN, 128, 0, stream>>>(x, Win, bin, A);
        k_step<false,false><<<NN/RPB, 128, 0, stream>>>(adj, dist, A, B, Wu1, bu1, Wu2, bu2, gam, bet);
        k_step<false,false><<<NN/RPB, 128, 0, stream>>>(adj, dist, B, A, Wu1, bu1, Wu2, bu2, gam, bet);
        k_step<false,false><<<NN/RPB, 128, 0, stream>>>(adj, dist, A, d_out, Wu1, bu1, Wu2, bu2, gam, bet);
    } else if (ws_size >= hb32) {
        // Path B: fp32 ping-pong between ws and d_out (d_out is 2 MB fp32); final lands in d_out
        void* A = d_ws;
        void* B = d_out;
        k_h0<false><<<NN, 128, 0, stream>>>(x, Win, bin, A);
        k_step<false,false><<<NN/RPB, 128, 0, stream>>>(adj, dist, A, B, Wu1, bu1, Wu2, bu2, gam, bet);
        k_step<false,false><<<NN/RPB, 128, 0, stream>>>(adj, dist, B, A, Wu1, bu1, Wu2, bu2, gam, bet);
        k_step<false,false><<<NN/RPB, 128, 0, stream>>>(adj, dist, A, B, Wu1, bu1, Wu2, bu2, gam, bet);
    } else {
        // Path C: bf16 h staging: ws (1 MB bf16) <-> d_out-as-bf16; final step writes fp32 d_out
        void* A = d_ws;
        void* B = d_out;
        k_h0<true><<<NN, 128, 0, stream>>>(x, Win, bin, A);
        k_step<true,true ><<<NN/RPB, 128, 0, stream>>>(adj, dist, A, B, Wu1, bu1, Wu2, bu2, gam, bet);
        k_step<true,true ><<<NN/RPB, 128, 0, stream>>>(adj, dist, B, A, Wu1, bu1, Wu2, bu2, gam, bet);
        k_step<true,false><<<NN/RPB, 128, 0, stream>>>(adj, dist, A, d_out, Wu1, bu1, Wu2, bu2, gam, bet);
    }
}

// Round 6
// 314.111 us; speedup vs baseline: 2.1677x; 2.1677x over previous
//
#include <hip/hip_runtime.h>
#include <hip/hip_bf16.h>

#define NN   4096
#define HID  128
#define INFE 64
#define KE   160   // edge-list slots/row: Binomial(4096,0.02) max ~122 over 4096 rows
#define EPI  4     // edges per k_msg inner iteration
#define KMAX 192   // fallback fused kernel
#define CH   64
#define RPB  4

typedef unsigned short u16;

__device__ __forceinline__ float bfu(u16 u) { return __uint_as_float(((unsigned)u) << 16); }
__device__ __forceinline__ u16 f2b(float f) { __hip_bfloat16 h = __float2bfloat16(f); return *(u16*)&h; }

// ---- h0 = x @ W_in + b_in ----
template<bool DB>
__global__ __launch_bounds__(128) void k_h0(
    const float* __restrict__ x, const float* __restrict__ Win, const float* __restrict__ bin,
    void* __restrict__ hdst)
{
    __shared__ float xl[INFE];
    const int r = blockIdx.x;
    const int d = threadIdx.x;
    if (d < INFE) xl[d] = x[(size_t)r*INFE + d];
    __syncthreads();
    float acc = bin[d];
    #pragma unroll 8
    for (int k = 0; k < INFE; ++k)
        acc = fmaf(xl[k], Win[k*HID + d], acc);
    if (DB) ((u16*)hdst)[(size_t)r*HID + d] = f2b(acc);
    else    ((float*)hdst)[(size_t)r*HID + d] = acc;
}

// ---- one-shot edge build: compact adj row + fold loop-invariant distance terms ----
// edges[r*KE+i] = {col (int bits), w1=adj*exp(-d/3), w2=adj*0.1*lj, 0}
__global__ __launch_bounds__(256) void k_build(
    const float* __restrict__ adj, const float* __restrict__ dist,
    float4* __restrict__ edges, int* __restrict__ nnzp)
{
    __shared__ int cnt;
    __shared__ int cl[KE];
    __shared__ float w1l[KE], w2l[KE];
    const int r = blockIdx.x;
    const int t = threadIdx.x;
    if (t == 0) cnt = 0;
    __syncthreads();
    const float4* arow = (const float4*)(adj + (size_t)r*NN);
    const float*  drow = dist + (size_t)r*NN;
    for (int c4 = t; c4 < NN/4; c4 += 256) {
        float4 a4 = arow[c4];
        if (a4.x != 0.f || a4.y != 0.f || a4.z != 0.f || a4.w != 0.f) {
            float av4[4] = {a4.x, a4.y, a4.z, a4.w};
            #pragma unroll
            for (int q = 0; q < 4; ++q) {
                float av = av4[q];
                if (av != 0.f) {
                    int c = 4*c4 + q;
                    float d  = fmaxf(drow[c], 1e-6f);
                    float dw1 = av * __expf(-d * (1.0f/3.0f));
                    float tt = 3.5f / d, t2 = tt*tt, t6 = t2*t2*t2;
                    float dw2 = av * 0.04f * (t6*t6 - t6);
                    int pos = atomicAdd(&cnt, 1);
                    if (pos < KE) { cl[pos] = c; w1l[pos] = dw1; w2l[pos] = dw2; }
                }
            }
        }
    }
    __syncthreads();
    int n  = cnt < KE ? cnt : KE;
    int np = (n + EPI - 1) / EPI * EPI;          // pad with null edges (w=0 -> no-op)
    for (int i = n + t; i < np; i += 256) { cl[i] = 0; w1l[i] = 0.f; w2l[i] = 0.f; }
    __syncthreads();
    float4* erow = edges + (size_t)r*KE;
    for (int i = t; i < np; i += 256)
        erow[i] = make_float4(__int_as_float(cl[i]), w1l[i], w2l[i], 0.f);
    if (t == 0) nnzp[r] = np;
}

// ---- message pass: one wave per row, barrier-free, registers only ----
// lane owns dims {2l, 2l+1}; per edge: coalesced h_j float2 load, shfl-xor dot, accumulate.
__global__ __launch_bounds__(256) void k_msg(
    const float4* __restrict__ edges, const int* __restrict__ nnzp,
    const float* __restrict__ h, float* __restrict__ m)
{
    const int r    = (blockIdx.x*256 + threadIdx.x) >> 6;   // 4096 waves = 4096 rows
    const int lane = threadIdx.x & 63;
    const float4* erow = edges + (size_t)r*KE;
    const int np = nnzp[r];
    const float2 hi = *(const float2*)(h + (size_t)r*HID + 2*lane);
    float m0 = 0.f, m1 = 0.f;
    for (int e0 = 0; e0 < np; e0 += EPI) {
        float4 ed[EPI]; float2 hj[EPI]; float p[EPI];
        #pragma unroll
        for (int q = 0; q < EPI; ++q) ed[q] = erow[e0 + q];        // wave-uniform
        #pragma unroll
        for (int q = 0; q < EPI; ++q) {
            int c = __float_as_int(ed[q].x);
            hj[q] = *(const float2*)(h + (size_t)c*HID + 2*lane);  // 512B coalesced, L2-hot
        }
        #pragma unroll
        for (int q = 0; q < EPI; ++q)
            p[q] = fmaf(hi.x, hj[q].x, hi.y * hj[q].y);
        #pragma unroll
        for (int mask = 1; mask < 64; mask <<= 1) {                // 4 independent chains
            #pragma unroll
            for (int q = 0; q < EPI; ++q) p[q] += __shfl_xor(p[q], mask);
        }
        #pragma unroll
        for (int q = 0; q < EPI; ++q) {
            float w = fmaf(ed[q].y, fmaxf(p[q], 0.f), ed[q].z);
            m0 = fmaf(w, hj[q].x, m0);
            m1 = fmaf(w, hj[q].y, m1);
        }
    }
    *(float2*)(m + (size_t)r*HID + 2*lane) = make_float2(m0, m1);
}

// ---- update MLP + residual + LayerNorm: 4 rows per 128-thr block ----
__global__ __launch_bounds__(128) void k_mlp(
    const float* __restrict__ h, const float* __restrict__ m,
    const float* __restrict__ Wu1, const float* __restrict__ bu1,
    const float* __restrict__ Wu2, const float* __restrict__ bu2,
    const float* __restrict__ gam, const float* __restrict__ bet,
    float* __restrict__ hout)
{
    __shared__ __align__(16) float conc[RPB][256];
    __shared__ __align__(16) float h1s[RPB][HID];
    __shared__ float hn[RPB][HID];
    const int r0 = blockIdx.x * RPB;
    const int t  = threadIdx.x;
    for (int i = t; i < RPB*256; i += 128) {
        int rr = i >> 8, k = i & 255;
        conc[rr][k] = (k < HID) ? h[(size_t)(r0+rr)*HID + k]
                                : m[(size_t)(r0+rr)*HID + (k - HID)];
    }
    __syncthreads();
    {
        float bb = bu1[t];
        float a0 = bb, a1 = bb, a2 = bb, a3 = bb;
        for (int k = 0; k < 256; k += 4) {
            float w0 = Wu1[(k+0)*HID + t];
            float w1 = Wu1[(k+1)*HID + t];
            float w2 = Wu1[(k+2)*HID + t];
            float w3 = Wu1[(k+3)*HID + t];
            float4 c0 = *(const float4*)&conc[0][k];
            float4 c1 = *(const float4*)&conc[1][k];
            float4 c2 = *(const float4*)&conc[2][k];
            float4 c3 = *(const float4*)&conc[3][k];
            a0 = fmaf(c0.x,w0,a0); a0 = fmaf(c0.y,w1,a0); a0 = fmaf(c0.z,w2,a0); a0 = fmaf(c0.w,w3,a0);
            a1 = fmaf(c1.x,w0,a1); a1 = fmaf(c1.y,w1,a1); a1 = fmaf(c1.z,w2,a1); a1 = fmaf(c1.w,w3,a1);
            a2 = fmaf(c2.x,w0,a2); a2 = fmaf(c2.y,w1,a2); a2 = fmaf(c2.z,w2,a2); a2 = fmaf(c2.w,w3,a2);
            a3 = fmaf(c3.x,w0,a3); a3 = fmaf(c3.y,w1,a3); a3 = fmaf(c3.z,w2,a3); a3 = fmaf(c3.w,w3,a3);
        }
        h1s[0][t] = fmaxf(a0,0.f); h1s[1][t] = fmaxf(a1,0.f);
        h1s[2][t] = fmaxf(a2,0.f); h1s[3][t] = fmaxf(a3,0.f);
    }
    __syncthreads();
    {
        float bb = bu2[t];
        float b0 = bb, b1 = bb, b2 = bb, b3 = bb;
        for (int k = 0; k < HID; k += 4) {
            float w0 = Wu2[(k+0)*HID + t];
            float w1 = Wu2[(k+1)*HID + t];
            float w2 = Wu2[(k+2)*HID + t];
            float w3 = Wu2[(k+3)*HID + t];
            float4 c0 = *(const float4*)&h1s[0][k];
            float4 c1 = *(const float4*)&h1s[1][k];
            float4 c2 = *(const float4*)&h1s[2][k];
            float4 c3 = *(const float4*)&h1s[3][k];
            b0 = fmaf(c0.x,w0,b0); b0 = fmaf(c0.y,w1,b0); b0 = fmaf(c0.z,w2,b0); b0 = fmaf(c0.w,w3,b0);
            b1 = fmaf(c1.x,w0,b1); b1 = fmaf(c1.y,w1,b1); b1 = fmaf(c1.z,w2,b1); b1 = fmaf(c1.w,w3,b1);
            b2 = fmaf(c2.x,w0,b2); b2 = fmaf(c2.y,w1,b2); b2 = fmaf(c2.z,w2,b2); b2 = fmaf(c2.w,w3,b2);
            b3 = fmaf(c3.x,w0,b3); b3 = fmaf(c3.y,w1,b3); b3 = fmaf(c3.z,w2,b3); b3 = fmaf(c3.w,w3,b3);
        }
        hn[0][t] = conc[0][t] + b0;
        hn[1][t] = conc[1][t] + b1;
        hn[2][t] = conc[2][t] + b2;
        hn[3][t] = conc[3][t] + b3;
    }
    __syncthreads();
    {
        const int lr = t >> 5, j = t & 31;
        float s = 0.f;
        #pragma unroll
        for (int q = 0; q < 4; ++q) s += hn[lr][j + 32*q];
        #pragma unroll
        for (int k2 = 16; k2 >= 1; k2 >>= 1) s += __shfl_xor(s, k2);
        float mu = s * (1.0f/128.0f);
        float v = 0.f;
        #pragma unroll
        for (int q = 0; q < 4; ++q) { float z = hn[lr][j + 32*q] - mu; v = fmaf(z, z, v); }
        #pragma unroll
        for (int k2 = 16; k2 >= 1; k2 >>= 1) v += __shfl_xor(v, k2);
        float rstd = rsqrtf(v * (1.0f/128.0f) + 1e-5f);
        #pragma unroll
        for (int q = 0; q < 4; ++q) {
            int dd = j + 32*q;
            hout[(size_t)(r0+lr)*HID + dd] = fmaf((hn[lr][dd] - mu) * rstd, gam[dd], bet[dd]);
        }
    }
}

// ================= fallback fused kernel (R5, proven correct) =================
template<bool SB, bool DB>
__global__ __launch_bounds__(128) void k_step(
    const float* __restrict__ adj, const float* __restrict__ dist,
    const void* hsrc, void* hdst,
    const float* __restrict__ Wu1, const float* __restrict__ bu1,
    const float* __restrict__ Wu2, const float* __restrict__ bu2,
    const float* __restrict__ gam, const float* __restrict__ bet)
{
    __shared__ int   cnt4[RPB];
    __shared__ int   cl[RPB][KMAX];
    __shared__ float w1l[RPB][KMAX], w2l[RPB][KMAX];
    __shared__ __align__(16) float hs4[RPB][HID];
    __shared__ __align__(16) float hj[CH][HID + 1];
    __shared__ float pl[CH];
    __shared__ __align__(16) float ms[RPB][HID];
    __shared__ __align__(16) float h1s[RPB][HID];
    __shared__ float hn[RPB][HID];
    const int r0 = blockIdx.x * RPB;
    const int t  = threadIdx.x;
    const u16*   s16 = (const u16*)hsrc;
    const float* s32 = (const float*)hsrc;
    if (t < RPB) cnt4[t] = 0;
    for (int i = t; i < RPB*HID; i += 128) {
        int rr = i >> 7, d = i & 127;
        hs4[rr][d] = SB ? bfu(s16[(size_t)(r0+rr)*HID + d]) : s32[(size_t)(r0+rr)*HID + d];
    }
    __syncthreads();
    for (int idx = t; idx < RPB*(NN/4); idx += 128) {
        int rr = idx >> 10, c4 = idx & 1023;
        float4 a4 = ((const float4*)(adj + (size_t)(r0+rr)*NN))[c4];
        if (a4.x != 0.f || a4.y != 0.f || a4.z != 0.f || a4.w != 0.f) {
            const float* drow = dist + (size_t)(r0+rr)*NN;
            float av4[4] = {a4.x, a4.y, a4.z, a4.w};
            #pragma unroll
            for (int q = 0; q < 4; ++q) {
                float av = av4[q];
                if (av != 0.f) {
                    int c = 4*c4 + q;
                    float d  = fmaxf(drow[c], 1e-6f);
                    float dw1 = av * __expf(-d * (1.0f/3.0f));
                    float tt = 3.5f / d, t2 = tt*tt, t6 = t2*t2*t2;
                    float dw2 = av * 0.04f * (t6*t6 - t6);
                    int pos = atomicAdd(&cnt4[rr], 1);
                    if (pos < KMAX) { cl[rr][pos] = c; w1l[rr][pos] = dw1; w2l[rr][pos] = dw2; }
                }
            }
        }
    }
    __syncthreads();
    int npv[RPB];
    for (int rr = 0; rr < RPB; ++rr) {
        int n  = cnt4[rr] < KMAX ? cnt4[rr] : KMAX;
        int np = (n + CH - 1) / CH * CH;
        npv[rr] = np;
        for (int i = n + t; i < np; i += 128) { cl[rr][i] = 0; w1l[rr][i] = 0.f; w2l[rr][i] = 0.f; }
    }
    __syncthreads();
    const int e2 = t >> 1, hf = t & 1;
    for (int rr = 0; rr < RPB; ++rr) {
        float acc = 0.f;
        for (int e0 = 0; e0 < npv[rr]; e0 += CH) {
            int c = cl[rr][e0 + e2];
            float* dst = &hj[e2][hf*64];
            if (SB) {
                const uint4* sv = (const uint4*)(s16 + (size_t)c*HID + hf*64);
                #pragma unroll
                for (int i = 0; i < 8; ++i) {
                    uint4 v = sv[i];
                    dst[8*i+0] = __uint_as_float(v.x << 16); dst[8*i+1] = __uint_as_float(v.x & 0xffff0000u);
                    dst[8*i+2] = __uint_as_float(v.y << 16); dst[8*i+3] = __uint_as_float(v.y & 0xffff0000u);
                    dst[8*i+4] = __uint_as_float(v.z << 16); dst[8*i+5] = __uint_as_float(v.z & 0xffff0000u);
                    dst[8*i+6] = __uint_as_float(v.w << 16); dst[8*i+7] = __uint_as_float(v.w & 0xffff0000u);
                }
            } else {
                const float4* sv = (const float4*)(s32 + (size_t)c*HID + hf*64);
                #pragma unroll
                for (int i = 0; i < 16; ++i) {
                    float4 v = sv[i];
                    dst[4*i+0] = v.x; dst[4*i+1] = v.y; dst[4*i+2] = v.z; dst[4*i+3] = v.w;
                }
            }
            __syncthreads();
            {
                const float* ha = &hs4[rr][hf*64];
                const float* hb = &hj[e2][hf*64];
                float p = 0.f;
                #pragma unroll
                for (int i = 0; i < 64; ++i) p = fmaf(ha[i], hb[i], p);
                p += __shfl_xor(p, 1);
                if (hf == 0) pl[e2] = fmaf(w1l[rr][e0+e2], fmaxf(p, 0.f), w2l[rr][e0+e2]);
            }
            __syncthreads();
            #pragma unroll
            for (int i = 0; i < CH; ++i) acc = fmaf(pl[i], hj[i][t], acc);
            __syncthreads();
        }
        ms[rr][t] = acc;
    }
    __syncthreads();
    {
        float bb = bu1[t];
        float a0 = bb, a1 = bb, a2 = bb, a3 = bb;
        for (int k = 0; k < HID; k += 4) {
            float w0 = Wu1[(k+0)*HID + t], w1 = Wu1[(k+1)*HID + t];
            float w2 = Wu1[(k+2)*HID + t], w3 = Wu1[(k+3)*HID + t];
            float4 c0 = *(const float4*)&hs4[0][k];
            float4 c1 = *(const float4*)&hs4[1][k];
            float4 c2 = *(const float4*)&hs4[2][k];
            float4 c3 = *(const float4*)&hs4[3][k];
            a0 = fmaf(c0.x,w0,a0); a0 = fmaf(c0.y,w1,a0); a0 = fmaf(c0.z,w2,a0); a0 = fmaf(c0.w,w3,a0);
            a1 = fmaf(c1.x,w0,a1); a1 = fmaf(c1.y,w1,a1); a1 = fmaf(c1.z,w2,a1); a1 = fmaf(c1.w,w3,a1);
            a2 = fmaf(c2.x,w0,a2); a2 = fmaf(c2.y,w1,a2); a2 = fmaf(c2.z,w2,a2); a2 = fmaf(c2.w,w3,a2);
            a3 = fmaf(c3.x,w0,a3); a3 = fmaf(c3.y,w1,a3); a3 = fmaf(c3.z,w2,a3); a3 = fmaf(c3.w,w3,a3);
        }
        for (int k = 0; k < HID; k += 4) {
            float w0 = Wu1[(HID+k+0)*HID + t], w1 = Wu1[(HID+k+1)*HID + t];
            float w2 = Wu1[(HID+k+2)*HID + t], w3 = Wu1[(HID+k+3)*HID + t];
            float4 c0 = *(const float4*)&ms[0][k];
            float4 c1 = *(const float4*)&ms[1][k];
            float4 c2 = *(const float4*)&ms[2][k];
            float4 c3 = *(const float4*)&ms[3][k];
            a0 = fmaf(c0.x,w0,a0); a0 = fmaf(c0.y,w1,a0); a0 = fmaf(c0.z,w2,a0); a0 = fmaf(c0.w,w3,a0);
            a1 = fmaf(c1.x,w0,a1); a1 = fmaf(c1.y,w1,a1); a1 = fmaf(c1.z,w2,a1); a1 = fmaf(c1.w,w3,a1);
            a2 = fmaf(c2.x,w0,a2); a2 = fmaf(c2.y,w1,a2); a2 = fmaf(c2.z,w2,a2); a2 = fmaf(c2.w,w3,a2);
            a3 = fmaf(c3.x,w0,a3); a3 = fmaf(c3.y,w1,a3); a3 = fmaf(c3.z,w2,a3); a3 = fmaf(c3.w,w3,a3);
        }
        h1s[0][t] = fmaxf(a0,0.f); h1s[1][t] = fmaxf(a1,0.f);
        h1s[2][t] = fmaxf(a2,0.f); h1s[3][t] = fmaxf(a3,0.f);
    }
    __syncthreads();
    {
        float bb = bu2[t];
        float b0 = bb, b1 = bb, b2 = bb, b3 = bb;
        for (int k = 0; k < HID; k += 4) {
            float w0 = Wu2[(k+0)*HID + t], w1 = Wu2[(k+1)*HID + t];
            float w2 = Wu2[(k+2)*HID + t], w3 = Wu2[(k+3)*HID + t];
            float4 c0 = *(const float4*)&h1s[0][k];
            float4 c1 = *(const float4*)&h1s[1][k];
            float4 c2 = *(const float4*)&h1s[2][k];
            float4 c3 = *(const float4*)&h1s[3][k];
            b0 = fmaf(c0.x,w0,b0); b0 = fmaf(c0.y,w1,b0); b0 = fmaf(c0.z,w2,b0); b0 = fmaf(c0.w,w3,b0);
            b1 = fmaf(c1.x,w0,b1); b1 = fmaf(c1.y,w1,b1); b1 = fmaf(c1.z,w2,b1); b1 = fmaf(c1.w,w3,b1);
            b2 = fmaf(c2.x,w0,b2); b2 = fmaf(c2.y,w1,b2); b2 = fmaf(c2.z,w2,b2); b2 = fmaf(c2.w,w3,b2);
            b3 = fmaf(c3.x,w0,b3); b3 = fmaf(c3.y,w1,b3); b3 = fmaf(c3.z,w2,b3); b3 = fmaf(c3.w,w3,b3);
        }
        hn[0][t] = hs4[0][t] + b0; hn[1][t] = hs4[1][t] + b1;
        hn[2][t] = hs4[2][t] + b2; hn[3][t] = hs4[3][t] + b3;
    }
    __syncthreads();
    {
        const int lr = t >> 5, j = t & 31;
        float s = 0.f;
        #pragma unroll
        for (int q = 0; q < 4; ++q) s += hn[lr][j + 32*q];
        #pragma unroll
        for (int k2 = 16; k2 >= 1; k2 >>= 1) s += __shfl_xor(s, k2);
        float mu = s * (1.0f/128.0f);
        float v = 0.f;
        #pragma unroll
        for (int q = 0; q < 4; ++q) { float z = hn[lr][j + 32*q] - mu; v = fmaf(z, z, v); }
        #pragma unroll
        for (int k2 = 16; k2 >= 1; k2 >>= 1) v += __shfl_xor(v, k2);
        float rstd = rsqrtf(v * (1.0f/128.0f) + 1e-5f);
        #pragma unroll
        for (int q = 0; q < 4; ++q) {
            int dd = j + 32*q;
            float val = fmaf((hn[lr][dd] - mu) * rstd, gam[dd], bet[dd]);
            if (DB) ((u16*)hdst)[(size_t)(r0+lr)*HID + dd] = f2b(val);
            else    ((float*)hdst)[(size_t)(r0+lr)*HID + dd] = val;
        }
    }
}

extern "C" void kernel_launch(void* const* d_in, const int* in_sizes, int n_in,
                              void* d_out, int out_size, void* d_ws, size_t ws_size,
                              hipStream_t stream)
{
    const float* x    = (const float*)d_in[0];
    const float* adj  = (const float*)d_in[1];
    const float* dist = (const float*)d_in[2];
    const float* Win  = (const float*)d_in[3];
    const float* bin  = (const float*)d_in[4];
    const float* Wu1  = (const float*)d_in[7];
    const float* bu1  = (const float*)d_in[8];
    const float* Wu2  = (const float*)d_in[9];
    const float* bu2  = (const float*)d_in[10];
    const float* gam  = (const float*)d_in[11];
    const float* bet  = (const float*)d_in[12];

    const size_t ebytes = (size_t)NN * KE * sizeof(float4);        // 10.49 MB
    const size_t nbytes = ((size_t)NN * sizeof(int) + 255) & ~255; // 16 KB
    const size_t hb32   = (size_t)NN * HID * sizeof(float);        // 2 MB
    const size_t need   = ebytes + nbytes + 2 * hb32;              // ~14.5 MB

    if (ws_size >= need) {
        // Fast path: build edges once, then 3x (wave-per-row msg + MLP)
        float4* edges = (float4*)d_ws;
        int*    nnzp  = (int*)((char*)d_ws + ebytes);
        float*  hA    = (float*)((char*)d_ws + ebytes + nbytes);
        float*  mb    = (float*)((char*)d_ws + ebytes + nbytes + hb32);
        float*  hB    = (float*)d_out;   // ping-pong partner; final result lands here

        k_build<<<NN, 256, 0, stream>>>(adj, dist, edges, nnzp);
        k_h0<false><<<NN, 128, 0, stream>>>(x, Win, bin, hA);
        // step 1: hA -> hB(d_out)
        k_msg<<<NN/4, 256, 0, stream>>>(edges, nnzp, hA, mb);
        k_mlp<<<NN/RPB, 128, 0, stream>>>(hA, mb, Wu1, bu1, Wu2, bu2, gam, bet, hB);
        // step 2: hB -> hA
        k_msg<<<NN/4, 256, 0, stream>>>(edges, nnzp, hB, mb);
        k_mlp<<<NN/RPB, 128, 0, stream>>>(hB, mb, Wu1, bu1, Wu2, bu2, gam, bet, hA);
        // step 3: hA -> d_out
        k_msg<<<NN/4, 256, 0, stream>>>(edges, nnzp, hA, mb);
        k_mlp<<<NN/RPB, 128, 0, stream>>>(hA, mb, Wu1, bu1, Wu2, bu2, gam, bet, hB);
    } else if (ws_size >= hb32) {
        // Fallback (R5 path B): fp32 ping-pong ws <-> d_out
        void* A = d_ws; void* B = d_out;
        k_h0<false><<<NN, 128, 0, stream>>>(x, Win, bin, A);
        k_step<false,false><<<NN/RPB, 128, 0, stream>>>(adj, dist, A, B, Wu1, bu1, Wu2, bu2, gam, bet);
        k_step<false,false><<<NN/RPB, 128, 0, stream>>>(adj, dist, B, A, Wu1, bu1, Wu2, bu2, gam, bet);
        k_step<false,false><<<NN/RPB, 128, 0, stream>>>(adj, dist, A, B, Wu1, bu1, Wu2, bu2, gam, bet);
    } else {
        // Fallback (R5 path C): bf16 h staging, final fp32
        void* A = d_ws; void* B = d_out;
        k_h0<true><<<NN, 128, 0, stream>>>(x, Win, bin, A);
        k_step<true,true ><<<NN/RPB, 128, 0, stream>>>(adj, dist, A, B, Wu1, bu1, Wu2, bu2, gam, bet);
        k_step<true,true ><<<NN/RPB, 128, 0, stream>>>(adj, dist, B, A, Wu1, bu1, Wu2, bu2, gam, bet);
        k_step<true,false><<<NN/RPB, 128, 0, stream>>>(adj, dist, A, d_out, Wu1, bu1, Wu2, bu2, gam, bet);
    }
}

// Round 7
// 284.067 us; speedup vs baseline: 2.3970x; 1.1058x over previous
//
#include <hip/hip_runtime.h>
#include <hip/hip_bf16.h>

#define NN   4096
#define HID  128
#define INFE 64
#define KE   160   // edge slots/row: Binomial(4096,0.02) max ~122 across 4096 rows
#define KMAX 192   // fallback fused kernel
#define CH   64
#define RPB  4

typedef unsigned short u16;

__device__ __forceinline__ float bfu(u16 u) { return __uint_as_float(((unsigned)u) << 16); }
__device__ __forceinline__ u16 f2b(float f) { __hip_bfloat16 h = __float2bfloat16(f); return *(u16*)&h; }

// ---- h0 = x @ W_in + b_in ----
template<bool DB>
__global__ __launch_bounds__(128) void k_h0(
    const float* __restrict__ x, const float* __restrict__ Win, const float* __restrict__ bin,
    void* __restrict__ hdst)
{
    __shared__ float xl[INFE];
    const int r = blockIdx.x;
    const int d = threadIdx.x;
    if (d < INFE) xl[d] = x[(size_t)r*INFE + d];
    __syncthreads();
    float acc = bin[d];
    #pragma unroll 8
    for (int k = 0; k < INFE; ++k)
        acc = fmaf(xl[k], Win[k*HID + d], acc);
    if (DB) ((u16*)hdst)[(size_t)r*HID + d] = f2b(acc);
    else    ((float*)hdst)[(size_t)r*HID + d] = acc;
}

// ---- one-shot edge build: compact adj row + fold loop-invariant distance terms ----
// edges[r*KE+i] = {col (int bits), w1=adj*exp(-d/3), w2=adj*0.1*lj, 0}; np padded to x4
__global__ __launch_bounds__(256) void k_build(
    const float* __restrict__ adj, const float* __restrict__ dist,
    float4* __restrict__ edges, int* __restrict__ nnzp)
{
    __shared__ int cnt;
    __shared__ int cl[KE];
    __shared__ float w1l[KE], w2l[KE];
    const int r = blockIdx.x;
    const int t = threadIdx.x;
    if (t == 0) cnt = 0;
    __syncthreads();
    const float4* arow = (const float4*)(adj + (size_t)r*NN);
    const float*  drow = dist + (size_t)r*NN;
    // 4 upfront loads per thread -> 4 outstanding HBM requests (MLP)
    float4 av[4];
    #pragma unroll
    for (int q = 0; q < 4; ++q) av[q] = arow[t + 256*q];
    #pragma unroll
    for (int q = 0; q < 4; ++q) {
        float a4[4] = {av[q].x, av[q].y, av[q].z, av[q].w};
        if (a4[0] != 0.f || a4[1] != 0.f || a4[2] != 0.f || a4[3] != 0.f) {
            #pragma unroll
            for (int u = 0; u < 4; ++u) {
                float a = a4[u];
                if (a != 0.f) {
                    int c = 4*(t + 256*q) + u;
                    float d  = fmaxf(drow[c], 1e-6f);
                    float dw1 = a * __expf(-d * (1.0f/3.0f));
                    float tt = 3.5f / d, t2 = tt*tt, t6 = t2*t2*t2;
                    float dw2 = a * 0.04f * (t6*t6 - t6);
                    int pos = atomicAdd(&cnt, 1);
                    if (pos < KE) { cl[pos] = c; w1l[pos] = dw1; w2l[pos] = dw2; }
                }
            }
        }
    }
    __syncthreads();
    int n  = cnt < KE ? cnt : KE;
    int np = (n + 3) / 4 * 4;                    // pad to x4 with null edges (w=0)
    for (int i = n + t; i < np; i += 256) { cl[i] = 0; w1l[i] = 0.f; w2l[i] = 0.f; }
    __syncthreads();
    float4* erow = edges + (size_t)r*KE;
    for (int i = t; i < np; i += 256)
        erow[i] = make_float4(__int_as_float(cl[i]), w1l[i], w2l[i], 0.f);
    if (t == 0) nnzp[r] = np;
}

// ---- fused step: message (wave/row, 32-lane dot groups) + MLP + residual + LN ----
// 256 threads = 4 waves = 4 rows. Messages stay in LDS; 8 KB LDS total.
__global__ __launch_bounds__(256) void k_fstep(
    const float4* __restrict__ edges, const int* __restrict__ nnzp,
    const float* __restrict__ h,
    const float* __restrict__ Wu1, const float* __restrict__ bu1,
    const float* __restrict__ Wu2, const float* __restrict__ bu2,
    const float* __restrict__ gam, const float* __restrict__ bet,
    float* __restrict__ hout)
{
    __shared__ __align__(16) float hs[RPB][HID];
    __shared__ __align__(16) float ms[RPB][HID];
    __shared__ __align__(16) float h1s[RPB][HID];
    __shared__ float hn[RPB][HID];
    const int t    = threadIdx.x;
    const int w    = t >> 6;        // wave id = local row
    const int lane = t & 63;
    const int g    = lane >> 5;     // half: edge parity
    const int j    = lane & 31;     // sublane: owns dims 4j..4j+3
    const int r0   = blockIdx.x * RPB;
    const int r    = r0 + w;

    // ---- message phase (barrier-free within wave) ----
    const float4 hi4 = *(const float4*)(h + (size_t)r*HID + 4*j);
    if (g == 0) *(float4*)&hs[w][4*j] = hi4;
    const float4* erow = edges + (size_t)r*KE;
    const int np = nnzp[r];
    float4 macc = make_float4(0.f, 0.f, 0.f, 0.f);
    for (int e0 = 0; e0 < np; e0 += 4) {
        // two pairs: this half handles edges e0+g and e0+2+g
        float4 edA = erow[e0 + g];
        float4 edB = erow[e0 + 2 + g];
        int cA = __float_as_int(edA.x);
        int cB = __float_as_int(edB.x);
        float4 hjA = *(const float4*)(h + (size_t)cA*HID + 4*j);
        float4 hjB = *(const float4*)(h + (size_t)cB*HID + 4*j);
        float pA = hi4.x*hjA.x; pA = fmaf(hi4.y, hjA.y, pA); pA = fmaf(hi4.z, hjA.z, pA); pA = fmaf(hi4.w, hjA.w, pA);
        float pB = hi4.x*hjB.x; pB = fmaf(hi4.y, hjB.y, pB); pB = fmaf(hi4.z, hjB.z, pB); pB = fmaf(hi4.w, hjB.w, pB);
        #pragma unroll
        for (int mask = 1; mask <= 16; mask <<= 1) {     // stays within 32-lane half
            pA += __shfl_xor(pA, mask);
            pB += __shfl_xor(pB, mask);
        }
        float wA = fmaf(edA.y, fmaxf(pA, 0.f), edA.z);
        float wB = fmaf(edB.y, fmaxf(pB, 0.f), edB.z);
        macc.x = fmaf(wA, hjA.x, macc.x); macc.y = fmaf(wA, hjA.y, macc.y);
        macc.z = fmaf(wA, hjA.z, macc.z); macc.w = fmaf(wA, hjA.w, macc.w);
        macc.x = fmaf(wB, hjB.x, macc.x); macc.y = fmaf(wB, hjB.y, macc.y);
        macc.z = fmaf(wB, hjB.z, macc.z); macc.w = fmaf(wB, hjB.w, macc.w);
    }
    // combine the two halves' edge subsets
    macc.x += __shfl_xor(macc.x, 32);
    macc.y += __shfl_xor(macc.y, 32);
    macc.z += __shfl_xor(macc.z, 32);
    macc.w += __shfl_xor(macc.w, 32);
    if (g == 0) *(float4*)&ms[w][4*j] = macc;
    __syncthreads();

    // ---- MLP phase A: h1 = relu([h,m] @ Wu1 + b1); thread (half,d) does rows 2*half,2*half+1
    {
        const int half = t >> 7;
        const int d    = t & 127;
        const int ra = 2*half, rb = ra + 1;
        float bb = bu1[d];
        float a0 = bb, a1 = bb;
        for (int k = 0; k < HID; k += 4) {
            float w0 = Wu1[(k+0)*HID + d], w1 = Wu1[(k+1)*HID + d];
            float w2 = Wu1[(k+2)*HID + d], w3 = Wu1[(k+3)*HID + d];
            float4 ca = *(const float4*)&hs[ra][k];
            float4 cb = *(const float4*)&hs[rb][k];
            a0 = fmaf(ca.x,w0,a0); a0 = fmaf(ca.y,w1,a0); a0 = fmaf(ca.z,w2,a0); a0 = fmaf(ca.w,w3,a0);
            a1 = fmaf(cb.x,w0,a1); a1 = fmaf(cb.y,w1,a1); a1 = fmaf(cb.z,w2,a1); a1 = fmaf(cb.w,w3,a1);
        }
        for (int k = 0; k < HID; k += 4) {
            float w0 = Wu1[(HID+k+0)*HID + d], w1 = Wu1[(HID+k+1)*HID + d];
            float w2 = Wu1[(HID+k+2)*HID + d], w3 = Wu1[(HID+k+3)*HID + d];
            float4 ca = *(const float4*)&ms[ra][k];
            float4 cb = *(const float4*)&ms[rb][k];
            a0 = fmaf(ca.x,w0,a0); a0 = fmaf(ca.y,w1,a0); a0 = fmaf(ca.z,w2,a0); a0 = fmaf(ca.w,w3,a0);
            a1 = fmaf(cb.x,w0,a1); a1 = fmaf(cb.y,w1,a1); a1 = fmaf(cb.z,w2,a1); a1 = fmaf(cb.w,w3,a1);
        }
        h1s[ra][d] = fmaxf(a0, 0.f);
        h1s[rb][d] = fmaxf(a1, 0.f);
    }
    __syncthreads();
    // ---- MLP phase B: hn = h + (h1 @ Wu2 + b2)
    {
        const int half = t >> 7;
        const int d    = t & 127;
        const int ra = 2*half, rb = ra + 1;
        float bb = bu2[d];
        float b0 = bb, b1 = bb;
        for (int k = 0; k < HID; k += 4) {
            float w0 = Wu2[(k+0)*HID + d], w1 = Wu2[(k+1)*HID + d];
            float w2 = Wu2[(k+2)*HID + d], w3 = Wu2[(k+3)*HID + d];
            float4 ca = *(const float4*)&h1s[ra][k];
            float4 cb = *(const float4*)&h1s[rb][k];
            b0 = fmaf(ca.x,w0,b0); b0 = fmaf(ca.y,w1,b0); b0 = fmaf(ca.z,w2,b0); b0 = fmaf(ca.w,w3,b0);
            b1 = fmaf(cb.x,w0,b1); b1 = fmaf(cb.y,w1,b1); b1 = fmaf(cb.z,w2,b1); b1 = fmaf(cb.w,w3,b1);
        }
        hn[ra][d] = hs[ra][d] + b0;
        hn[rb][d] = hs[rb][d] + b1;
    }
    __syncthreads();
    // ---- LayerNorm: one wave per row, lane owns dims {lane, lane+64}
    {
        float v0 = hn[w][lane], v1 = hn[w][lane + 64];
        float s = v0 + v1;
        #pragma unroll
        for (int mask = 1; mask <= 32; mask <<= 1) s += __shfl_xor(s, mask);
        float mu = s * (1.0f/128.0f);
        float z0 = v0 - mu, z1 = v1 - mu;
        float vv = fmaf(z0, z0, z1*z1);
        #pragma unroll
        for (int mask = 1; mask <= 32; mask <<= 1) vv += __shfl_xor(vv, mask);
        float rstd = rsqrtf(vv * (1.0f/128.0f) + 1e-5f);
        hout[(size_t)r*HID + lane]      = fmaf(z0 * rstd, gam[lane],      bet[lane]);
        hout[(size_t)r*HID + lane + 64] = fmaf(z1 * rstd, gam[lane + 64], bet[lane + 64]);
    }
}

// ================= fallback fused kernel (R5, proven correct) =================
template<bool SB, bool DB>
__global__ __launch_bounds__(128) void k_step(
    const float* __restrict__ adj, const float* __restrict__ dist,
    const void* hsrc, void* hdst,
    const float* __restrict__ Wu1, const float* __restrict__ bu1,
    const float* __restrict__ Wu2, const float* __restrict__ bu2,
    const float* __restrict__ gam, const float* __restrict__ bet)
{
    __shared__ int   cnt4[RPB];
    __shared__ int   cl[RPB][KMAX];
    __shared__ float w1l[RPB][KMAX], w2l[RPB][KMAX];
    __shared__ __align__(16) float hs4[RPB][HID];
    __shared__ __align__(16) float hj[CH][HID + 1];
    __shared__ float pl[CH];
    __shared__ __align__(16) float ms[RPB][HID];
    __shared__ __align__(16) float h1s[RPB][HID];
    __shared__ float hn[RPB][HID];
    const int r0 = blockIdx.x * RPB;
    const int t  = threadIdx.x;
    const u16*   s16 = (const u16*)hsrc;
    const float* s32 = (const float*)hsrc;
    if (t < RPB) cnt4[t] = 0;
    for (int i = t; i < RPB*HID; i += 128) {
        int rr = i >> 7, d = i & 127;
        hs4[rr][d] = SB ? bfu(s16[(size_t)(r0+rr)*HID + d]) : s32[(size_t)(r0+rr)*HID + d];
    }
    __syncthreads();
    for (int idx = t; idx < RPB*(NN/4); idx += 128) {
        int rr = idx >> 10, c4 = idx & 1023;
        float4 a4 = ((const float4*)(adj + (size_t)(r0+rr)*NN))[c4];
        if (a4.x != 0.f || a4.y != 0.f || a4.z != 0.f || a4.w != 0.f) {
            const float* drow = dist + (size_t)(r0+rr)*NN;
            float av4[4] = {a4.x, a4.y, a4.z, a4.w};
            #pragma unroll
            for (int q = 0; q < 4; ++q) {
                float av = av4[q];
                if (av != 0.f) {
                    int c = 4*c4 + q;
                    float d  = fmaxf(drow[c], 1e-6f);
                    float dw1 = av * __expf(-d * (1.0f/3.0f));
                    float tt = 3.5f / d, t2 = tt*tt, t6 = t2*t2*t2;
                    float dw2 = av * 0.04f * (t6*t6 - t6);
                    int pos = atomicAdd(&cnt4[rr], 1);
                    if (pos < KMAX) { cl[rr][pos] = c; w1l[rr][pos] = dw1; w2l[rr][pos] = dw2; }
                }
            }
        }
    }
    __syncthreads();
    int npv[RPB];
    for (int rr = 0; rr < RPB; ++rr) {
        int n  = cnt4[rr] < KMAX ? cnt4[rr] : KMAX;
        int np = (n + CH - 1) / CH * CH;
        npv[rr] = np;
        for (int i = n + t; i < np; i += 128) { cl[rr][i] = 0; w1l[rr][i] = 0.f; w2l[rr][i] = 0.f; }
    }
    __syncthreads();
    const int e2 = t >> 1, hf = t & 1;
    for (int rr = 0; rr < RPB; ++rr) {
        float acc = 0.f;
        for (int e0 = 0; e0 < npv[rr]; e0 += CH) {
            int c = cl[rr][e0 + e2];
            float* dst = &hj[e2][hf*64];
            if (SB) {
                const uint4* sv = (const uint4*)(s16 + (size_t)c*HID + hf*64);
                #pragma unroll
                for (int i = 0; i < 8; ++i) {
                    uint4 v = sv[i];
                    dst[8*i+0] = __uint_as_float(v.x << 16); dst[8*i+1] = __uint_as_float(v.x & 0xffff0000u);
                    dst[8*i+2] = __uint_as_float(v.y << 16); dst[8*i+3] = __uint_as_float(v.y & 0xffff0000u);
                    dst[8*i+4] = __uint_as_float(v.z << 16); dst[8*i+5] = __uint_as_float(v.z & 0xffff0000u);
                    dst[8*i+6] = __uint_as_float(v.w << 16); dst[8*i+7] = __uint_as_float(v.w & 0xffff0000u);
                }
            } else {
                const float4* sv = (const float4*)(s32 + (size_t)c*HID + hf*64);
                #pragma unroll
                for (int i = 0; i < 16; ++i) {
                    float4 v = sv[i];
                    dst[4*i+0] = v.x; dst[4*i+1] = v.y; dst[4*i+2] = v.z; dst[4*i+3] = v.w;
                }
            }
            __syncthreads();
            {
                const float* ha = &hs4[rr][hf*64];
                const float* hb = &hj[e2][hf*64];
                float p = 0.f;
                #pragma unroll
                for (int i = 0; i < 64; ++i) p = fmaf(ha[i], hb[i], p);
                p += __shfl_xor(p, 1);
                if (hf == 0) pl[e2] = fmaf(w1l[rr][e0+e2], fmaxf(p, 0.f), w2l[rr][e0+e2]);
            }
            __syncthreads();
            #pragma unroll
            for (int i = 0; i < CH; ++i) acc = fmaf(pl[i], hj[i][t], acc);
            __syncthreads();
        }
        ms[rr][t] = acc;
    }
    __syncthreads();
    {
        float bb = bu1[t];
        float a0 = bb, a1 = bb, a2 = bb, a3 = bb;
        for (int k = 0; k < HID; k += 4) {
            float w0 = Wu1[(k+0)*HID + t], w1 = Wu1[(k+1)*HID + t];
            float w2 = Wu1[(k+2)*HID + t], w3 = Wu1[(k+3)*HID + t];
            float4 c0 = *(const float4*)&hs4[0][k];
            float4 c1 = *(const float4*)&hs4[1][k];
            float4 c2 = *(const float4*)&hs4[2][k];
            float4 c3 = *(const float4*)&hs4[3][k];
            a0 = fmaf(c0.x,w0,a0); a0 = fmaf(c0.y,w1,a0); a0 = fmaf(c0.z,w2,a0); a0 = fmaf(c0.w,w3,a0);
            a1 = fmaf(c1.x,w0,a1); a1 = fmaf(c1.y,w1,a1); a1 = fmaf(c1.z,w2,a1); a1 = fmaf(c1.w,w3,a1);
            a2 = fmaf(c2.x,w0,a2); a2 = fmaf(c2.y,w1,a2); a2 = fmaf(c2.z,w2,a2); a2 = fmaf(c2.w,w3,a2);
            a3 = fmaf(c3.x,w0,a3); a3 = fmaf(c3.y,w1,a3); a3 = fmaf(c3.z,w2,a3); a3 = fmaf(c3.w,w3,a3);
        }
        for (int k = 0; k < HID; k += 4) {
            float w0 = Wu1[(HID+k+0)*HID + t], w1 = Wu1[(HID+k+1)*HID + t];
            float w2 = Wu1[(HID+k+2)*HID + t], w3 = Wu1[(HID+k+3)*HID + t];
            float4 c0 = *(const float4*)&ms[0][k];
            float4 c1 = *(const float4*)&ms[1][k];
            float4 c2 = *(const float4*)&ms[2][k];
            float4 c3 = *(const float4*)&ms[3][k];
            a0 = fmaf(c0.x,w0,a0); a0 = fmaf(c0.y,w1,a0); a0 = fmaf(c0.z,w2,a0); a0 = fmaf(c0.w,w3,a0);
            a1 = fmaf(c1.x,w0,a1); a1 = fmaf(c1.y,w1,a1); a1 = fmaf(c1.z,w2,a1); a1 = fmaf(c1.w,w3,a1);
            a2 = fmaf(c2.x,w0,a2); a2 = fmaf(c2.y,w1,a2); a2 = fmaf(c2.z,w2,a2); a2 = fmaf(c2.w,w3,a2);
            a3 = fmaf(c3.x,w0,a3); a3 = fmaf(c3.y,w1,a3); a3 = fmaf(c3.z,w2,a3); a3 = fmaf(c3.w,w3,a3);
        }
        h1s[0][t] = fmaxf(a0,0.f); h1s[1][t] = fmaxf(a1,0.f);
        h1s[2][t] = fmaxf(a2,0.f); h1s[3][t] = fmaxf(a3,0.f);
    }
    __syncthreads();
    {
        float bb = bu2[t];
        float b0 = bb, b1 = bb, b2 = bb, b3 = bb;
        for (int k = 0; k < HID; k += 4) {
            float w0 = Wu2[(k+0)*HID + t], w1 = Wu2[(k+1)*HID + t];
            float w2 = Wu2[(k+2)*HID + t], w3 = Wu2[(k+3)*HID + t];
            float4 c0 = *(const float4*)&h1s[0][k];
            float4 c1 = *(const float4*)&h1s[1][k];
            float4 c2 = *(const float4*)&h1s[2][k];
            float4 c3 = *(const float4*)&h1s[3][k];
            b0 = fmaf(c0.x,w0,b0); b0 = fmaf(c0.y,w1,b0); b0 = fmaf(c0.z,w2,b0); b0 = fmaf(c0.w,w3,b0);
            b1 = fmaf(c1.x,w0,b1); b1 = fmaf(c1.y,w1,b1); b1 = fmaf(c1.z,w2,b1); b1 = fmaf(c1.w,w3,b1);
            b2 = fmaf(c2.x,w0,b2); b2 = fmaf(c2.y,w1,b2); b2 = fmaf(c2.z,w2,b2); b2 = fmaf(c2.w,w3,b2);
            b3 = fmaf(c3.x,w0,b3); b3 = fmaf(c3.y,w1,b3); b3 = fmaf(c3.z,w2,b3); b3 = fmaf(c3.w,w3,b3);
        }
        hn[0][t] = hs4[0][t] + b0; hn[1][t] = hs4[1][t] + b1;
        hn[2][t] = hs4[2][t] + b2; hn[3][t] = hs4[3][t] + b3;
    }
    __syncthreads();
    {
        const int lr = t >> 5, j = t & 31;
        float s = 0.f;
        #pragma unroll
        for (int q = 0; q < 4; ++q) s += hn[lr][j + 32*q];
        #pragma unroll
        for (int k2 = 16; k2 >= 1; k2 >>= 1) s += __shfl_xor(s, k2);
        float mu = s * (1.0f/128.0f);
        float v = 0.f;
        #pragma unroll
        for (int q = 0; q < 4; ++q) { float z = hn[lr][j + 32*q] - mu; v = fmaf(z, z, v); }
        #pragma unroll
        for (int k2 = 16; k2 >= 1; k2 >>= 1) v += __shfl_xor(v, k2);
        float rstd = rsqrtf(v * (1.0f/128.0f) + 1e-5f);
        #pragma unroll
        for (int q = 0; q < 4; ++q) {
            int dd = j + 32*q;
            float val = fmaf((hn[lr][dd] - mu) * rstd, gam[dd], bet[dd]);
            if (DB) ((u16*)hdst)[(size_t)(r0+lr)*HID + dd] = f2b(val);
            else    ((float*)hdst)[(size_t)(r0+lr)*HID + dd] = val;
        }
    }
}

extern "C" void kernel_launch(void* const* d_in, const int* in_sizes, int n_in,
                              void* d_out, int out_size, void* d_ws, size_t ws_size,
                              hipStream_t stream)
{
    const float* x    = (const float*)d_in[0];
    const float* adj  = (const float*)d_in[1];
    const float* dist = (const float*)d_in[2];
    const float* Win  = (const float*)d_in[3];
    const float* bin  = (const float*)d_in[4];
    const float* Wu1  = (const float*)d_in[7];
    const float* bu1  = (const float*)d_in[8];
    const float* Wu2  = (const float*)d_in[9];
    const float* bu2  = (const float*)d_in[10];
    const float* gam  = (const float*)d_in[11];
    const float* bet  = (const float*)d_in[12];

    const size_t ebytes = (size_t)NN * KE * sizeof(float4);        // 10.49 MB
    const size_t nbytes = ((size_t)NN * sizeof(int) + 255) & ~255; // 16 KB
    const size_t hb32   = (size_t)NN * HID * sizeof(float);        // 2 MB
    const size_t need   = ebytes + nbytes + hb32;                  // ~12.5 MB

    if (ws_size >= need) {
        float4* edges = (float4*)d_ws;
        int*    nnzp  = (int*)((char*)d_ws + ebytes);
        float*  hA    = (float*)((char*)d_ws + ebytes + nbytes);
        float*  hB    = (float*)d_out;   // ping-pong partner; final result lands here

        k_build<<<NN, 256, 0, stream>>>(adj, dist, edges, nnzp);
        k_h0<false><<<NN, 128, 0, stream>>>(x, Win, bin, hA);
        k_fstep<<<NN/RPB, 256, 0, stream>>>(edges, nnzp, hA, Wu1, bu1, Wu2, bu2, gam, bet, hB);
        k_fstep<<<NN/RPB, 256, 0, stream>>>(edges, nnzp, hB, Wu1, bu1, Wu2, bu2, gam, bet, hA);
        k_fstep<<<NN/RPB, 256, 0, stream>>>(edges, nnzp, hA, Wu1, bu1, Wu2, bu2, gam, bet, hB);
    } else if (ws_size >= hb32) {
        void* A = d_ws; void* B = d_out;
        k_h0<false><<<NN, 128, 0, stream>>>(x, Win, bin, A);
        k_step<false,false><<<NN/RPB, 128, 0, stream>>>(adj, dist, A, B, Wu1, bu1, Wu2, bu2, gam, bet);
        k_step<false,false><<<NN/RPB, 128, 0, stream>>>(adj, dist, B, A, Wu1, bu1, Wu2, bu2, gam, bet);
        k_step<false,false><<<NN/RPB, 128, 0, stream>>>(adj, dist, A, B, Wu1, bu1, Wu2, bu2, gam, bet);
    } else {
        void* A = d_ws; void* B = d_out;
        k_h0<true><<<NN, 128, 0, stream>>>(x, Win, bin, A);
        k_step<true,true ><<<NN/RPB, 128, 0, stream>>>(adj, dist, A, B, Wu1, bu1, Wu2, bu2, gam, bet);
        k_step<true,true ><<<NN/RPB, 128, 0, stream>>>(adj, dist, B, A, Wu1, bu1, Wu2, bu2, gam, bet);
        k_step<true,false><<<NN/RPB, 128, 0, stream>>>(adj, dist, A, d_out, Wu1, bu1, Wu2, bu2, gam, bet);
    }
}

// Round 8
// 270.924 us; speedup vs baseline: 2.5132x; 1.0485x over previous
//
#include <hip/hip_runtime.h>
#include <hip/hip_bf16.h>

#define NN   4096
#define HID  128
#define INFE 64
#define KE   160   // edge slots/row: Binomial(4096,0.02) max ~122 across 4096 rows
#define KMAX 192   // fallback fused kernel
#define CH   64
#define RPB  4

typedef unsigned short u16;

__device__ __forceinline__ float bfu(u16 u) { return __uint_as_float(((unsigned)u) << 16); }
__device__ __forceinline__ u16 f2b(float f) { __hip_bfloat16 h = __float2bfloat16(f); return *(u16*)&h; }

// ---- h0 = x @ W_in + b_in ----
template<bool DB>
__global__ __launch_bounds__(128) void k_h0(
    const float* __restrict__ x, const float* __restrict__ Win, const float* __restrict__ bin,
    void* __restrict__ hdst)
{
    __shared__ float xl[INFE];
    const int r = blockIdx.x;
    const int d = threadIdx.x;
    if (d < INFE) xl[d] = x[(size_t)r*INFE + d];
    __syncthreads();
    float acc = bin[d];
    #pragma unroll 8
    for (int k = 0; k < INFE; ++k)
        acc = fmaf(xl[k], Win[k*HID + d], acc);
    if (DB) ((u16*)hdst)[(size_t)r*HID + d] = f2b(acc);
    else    ((float*)hdst)[(size_t)r*HID + d] = acc;
}

// ---- one-shot edge build, two-phase ----
// phase 1: pure adj stream -> LDS (col, a) list.  phase 2: all dist loads
// independent across threads, edges written straight to global (coalesced).
__global__ __launch_bounds__(256) void k_build(
    const float* __restrict__ adj, const float* __restrict__ dist,
    float4* __restrict__ edges, int* __restrict__ nnzp)
{
    __shared__ int cnt;
    __shared__ int   cl[KE];
    __shared__ float ca[KE];
    const int r = blockIdx.x;
    const int t = threadIdx.x;
    if (t == 0) cnt = 0;
    __syncthreads();
    const float4* arow = (const float4*)(adj + (size_t)r*NN);
    float4 av[4];
    #pragma unroll
    for (int q = 0; q < 4; ++q) av[q] = arow[t + 256*q];   // 4 outstanding 1KB/wave loads
    #pragma unroll
    for (int q = 0; q < 4; ++q) {
        float a4[4] = {av[q].x, av[q].y, av[q].z, av[q].w};
        if (a4[0] != 0.f || a4[1] != 0.f || a4[2] != 0.f || a4[3] != 0.f) {
            #pragma unroll
            for (int u = 0; u < 4; ++u) {
                if (a4[u] != 0.f) {
                    int pos = atomicAdd(&cnt, 1);
                    if (pos < KE) { cl[pos] = 4*(t + 256*q) + u; ca[pos] = a4[u]; }
                }
            }
        }
    }
    __syncthreads();
    const int n  = cnt < KE ? cnt : KE;
    const int np = (n + 3) / 4 * 4;                        // pad to x4 with null edges
    float4* erow = edges + (size_t)r*KE;
    for (int i = n + t; i < np; i += 256)
        erow[i] = make_float4(__int_as_float(0), 0.f, 0.f, 0.f);
    // phase 2: every thread's dist load independent -> full memory-level parallelism
    const float* drow = dist + (size_t)r*NN;
    for (int i = t; i < n; i += 256) {
        int   c = cl[i];
        float a = ca[i];
        float d  = fmaxf(drow[c], 1e-6f);
        float dw1 = a * __expf(-d * (1.0f/3.0f));
        float tt = 3.5f / d, t2 = tt*tt, t6 = t2*t2*t2;
        float dw2 = a * 0.04f * (t6*t6 - t6);              // 0.1 * 4*eps*(sr12-sr6)
        erow[i] = make_float4(__int_as_float(c), dw1, dw2, 0.f);
    }
    if (t == 0) nnzp[r] = np;
}

// ---- fused step: message (wave/row) + MLP + residual + LN; edges staged in LDS ----
__global__ __launch_bounds__(256) void k_fstep(
    const float4* __restrict__ edges, const int* __restrict__ nnzp,
    const float* __restrict__ h,
    const float* __restrict__ Wu1, const float* __restrict__ bu1,
    const float* __restrict__ Wu2, const float* __restrict__ bu2,
    const float* __restrict__ gam, const float* __restrict__ bet,
    float* __restrict__ hout)
{
    __shared__ __align__(16) float4 eds[RPB][KE];   // 10 KB staged edge lists
    __shared__ int npl[RPB];
    __shared__ __align__(16) float hs[RPB][HID];
    __shared__ __align__(16) float ms[RPB][HID];
    __shared__ __align__(16) float h1s[RPB][HID];
    __shared__ float hn[RPB][HID];
    const int t    = threadIdx.x;
    const int w    = t >> 6;        // wave id = local row
    const int lane = t & 63;
    const int g    = lane >> 5;     // half: edge parity
    const int j    = lane & 31;     // sublane: owns dims 4j..4j+3
    const int r0   = blockIdx.x * RPB;
    const int r    = r0 + w;

    if (t < RPB) npl[t] = nnzp[r0 + t];
    const float4 hi4 = *(const float4*)(h + (size_t)r*HID + 4*j);
    if (g == 0) *(float4*)&hs[w][4*j] = hi4;
    __syncthreads();
    // cooperative coalesced edge staging (256 threads, float4 each)
    #pragma unroll
    for (int rr = 0; rr < RPB; ++rr) {
        const float4* er = edges + (size_t)(r0+rr)*KE;
        for (int i = t; i < npl[rr]; i += 256) eds[rr][i] = er[i];
    }
    __syncthreads();

    // ---- message phase (barrier-free within wave; edges from LDS) ----
    const int np = npl[w];
    float4 macc = make_float4(0.f, 0.f, 0.f, 0.f);
    for (int e0 = 0; e0 < np; e0 += 4) {
        float4 edA = eds[w][e0 + g];        // 2-way LDS broadcast: free
        float4 edB = eds[w][e0 + 2 + g];
        int cA = __float_as_int(edA.x);
        int cB = __float_as_int(edB.x);
        float4 hjA = *(const float4*)(h + (size_t)cA*HID + 4*j);
        float4 hjB = *(const float4*)(h + (size_t)cB*HID + 4*j);
        float pA = hi4.x*hjA.x; pA = fmaf(hi4.y, hjA.y, pA); pA = fmaf(hi4.z, hjA.z, pA); pA = fmaf(hi4.w, hjA.w, pA);
        float pB = hi4.x*hjB.x; pB = fmaf(hi4.y, hjB.y, pB); pB = fmaf(hi4.z, hjB.z, pB); pB = fmaf(hi4.w, hjB.w, pB);
        #pragma unroll
        for (int mask = 1; mask <= 16; mask <<= 1) {   // stays within 32-lane half
            pA += __shfl_xor(pA, mask);
            pB += __shfl_xor(pB, mask);
        }
        float wA = fmaf(edA.y, fmaxf(pA, 0.f), edA.z);
        float wB = fmaf(edB.y, fmaxf(pB, 0.f), edB.z);
        macc.x = fmaf(wA, hjA.x, macc.x); macc.y = fmaf(wA, hjA.y, macc.y);
        macc.z = fmaf(wA, hjA.z, macc.z); macc.w = fmaf(wA, hjA.w, macc.w);
        macc.x = fmaf(wB, hjB.x, macc.x); macc.y = fmaf(wB, hjB.y, macc.y);
        macc.z = fmaf(wB, hjB.z, macc.z); macc.w = fmaf(wB, hjB.w, macc.w);
    }
    macc.x += __shfl_xor(macc.x, 32);
    macc.y += __shfl_xor(macc.y, 32);
    macc.z += __shfl_xor(macc.z, 32);
    macc.w += __shfl_xor(macc.w, 32);
    if (g == 0) *(float4*)&ms[w][4*j] = macc;
    __syncthreads();

    // ---- MLP phase A: h1 = relu([h,m] @ Wu1 + b1)
    {
        const int half = t >> 7;
        const int d    = t & 127;
        const int ra = 2*half, rb = ra + 1;
        float bb = bu1[d];
        float a0 = bb, a1 = bb;
        for (int k = 0; k < HID; k += 4) {
            float w0 = Wu1[(k+0)*HID + d], w1 = Wu1[(k+1)*HID + d];
            float w2 = Wu1[(k+2)*HID + d], w3 = Wu1[(k+3)*HID + d];
            float4 caa = *(const float4*)&hs[ra][k];
            float4 cbb = *(const float4*)&hs[rb][k];
            a0 = fmaf(caa.x,w0,a0); a0 = fmaf(caa.y,w1,a0); a0 = fmaf(caa.z,w2,a0); a0 = fmaf(caa.w,w3,a0);
            a1 = fmaf(cbb.x,w0,a1); a1 = fmaf(cbb.y,w1,a1); a1 = fmaf(cbb.z,w2,a1); a1 = fmaf(cbb.w,w3,a1);
        }
        for (int k = 0; k < HID; k += 4) {
            float w0 = Wu1[(HID+k+0)*HID + d], w1 = Wu1[(HID+k+1)*HID + d];
            float w2 = Wu1[(HID+k+2)*HID + d], w3 = Wu1[(HID+k+3)*HID + d];
            float4 caa = *(const float4*)&ms[ra][k];
            float4 cbb = *(const float4*)&ms[rb][k];
            a0 = fmaf(caa.x,w0,a0); a0 = fmaf(caa.y,w1,a0); a0 = fmaf(caa.z,w2,a0); a0 = fmaf(caa.w,w3,a0);
            a1 = fmaf(cbb.x,w0,a1); a1 = fmaf(cbb.y,w1,a1); a1 = fmaf(cbb.z,w2,a1); a1 = fmaf(cbb.w,w3,a1);
        }
        h1s[ra][d] = fmaxf(a0, 0.f);
        h1s[rb][d] = fmaxf(a1, 0.f);
    }
    __syncthreads();
    // ---- MLP phase B: hn = h + (h1 @ Wu2 + b2)
    {
        const int half = t >> 7;
        const int d    = t & 127;
        const int ra = 2*half, rb = ra + 1;
        float bb = bu2[d];
        float b0 = bb, b1 = bb;
        for (int k = 0; k < HID; k += 4) {
            float w0 = Wu2[(k+0)*HID + d], w1 = Wu2[(k+1)*HID + d];
            float w2 = Wu2[(k+2)*HID + d], w3 = Wu2[(k+3)*HID + d];
            float4 caa = *(const float4*)&h1s[ra][k];
            float4 cbb = *(const float4*)&h1s[rb][k];
            b0 = fmaf(caa.x,w0,b0); b0 = fmaf(caa.y,w1,b0); b0 = fmaf(caa.z,w2,b0); b0 = fmaf(caa.w,w3,b0);
            b1 = fmaf(cbb.x,w0,b1); b1 = fmaf(cbb.y,w1,b1); b1 = fmaf(cbb.z,w2,b1); b1 = fmaf(cbb.w,w3,b1);
        }
        hn[ra][d] = hs[ra][d] + b0;
        hn[rb][d] = hs[rb][d] + b1;
    }
    __syncthreads();
    // ---- LayerNorm: one wave per row, lane owns dims {lane, lane+64}
    {
        float v0 = hn[w][lane], v1 = hn[w][lane + 64];
        float s = v0 + v1;
        #pragma unroll
        for (int mask = 1; mask <= 32; mask <<= 1) s += __shfl_xor(s, mask);
        float mu = s * (1.0f/128.0f);
        float z0 = v0 - mu, z1 = v1 - mu;
        float vv = fmaf(z0, z0, z1*z1);
        #pragma unroll
        for (int mask = 1; mask <= 32; mask <<= 1) vv += __shfl_xor(vv, mask);
        float rstd = rsqrtf(vv * (1.0f/128.0f) + 1e-5f);
        hout[(size_t)r*HID + lane]      = fmaf(z0 * rstd, gam[lane],      bet[lane]);
        hout[(size_t)r*HID + lane + 64] = fmaf(z1 * rstd, gam[lane + 64], bet[lane + 64]);
    }
}

// ================= fallback fused kernel (R5, proven correct) =================
template<bool SB, bool DB>
__global__ __launch_bounds__(128) void k_step(
    const float* __restrict__ adj, const float* __restrict__ dist,
    const void* hsrc, void* hdst,
    const float* __restrict__ Wu1, const float* __restrict__ bu1,
    const float* __restrict__ Wu2, const float* __restrict__ bu2,
    const float* __restrict__ gam, const float* __restrict__ bet)
{
    __shared__ int   cnt4[RPB];
    __shared__ int   cl[RPB][KMAX];
    __shared__ float w1l[RPB][KMAX], w2l[RPB][KMAX];
    __shared__ __align__(16) float hs4[RPB][HID];
    __shared__ __align__(16) float hj[CH][HID + 1];
    __shared__ float pl[CH];
    __shared__ __align__(16) float ms[RPB][HID];
    __shared__ __align__(16) float h1s[RPB][HID];
    __shared__ float hn[RPB][HID];
    const int r0 = blockIdx.x * RPB;
    const int t  = threadIdx.x;
    const u16*   s16 = (const u16*)hsrc;
    const float* s32 = (const float*)hsrc;
    if (t < RPB) cnt4[t] = 0;
    for (int i = t; i < RPB*HID; i += 128) {
        int rr = i >> 7, d = i & 127;
        hs4[rr][d] = SB ? bfu(s16[(size_t)(r0+rr)*HID + d]) : s32[(size_t)(r0+rr)*HID + d];
    }
    __syncthreads();
    for (int idx = t; idx < RPB*(NN/4); idx += 128) {
        int rr = idx >> 10, c4 = idx & 1023;
        float4 a4 = ((const float4*)(adj + (size_t)(r0+rr)*NN))[c4];
        if (a4.x != 0.f || a4.y != 0.f || a4.z != 0.f || a4.w != 0.f) {
            const float* drow = dist + (size_t)(r0+rr)*NN;
            float av4[4] = {a4.x, a4.y, a4.z, a4.w};
            #pragma unroll
            for (int q = 0; q < 4; ++q) {
                float av = av4[q];
                if (av != 0.f) {
                    int c = 4*c4 + q;
                    float d  = fmaxf(drow[c], 1e-6f);
                    float dw1 = av * __expf(-d * (1.0f/3.0f));
                    float tt = 3.5f / d, t2 = tt*tt, t6 = t2*t2*t2;
                    float dw2 = av * 0.04f * (t6*t6 - t6);
                    int pos = atomicAdd(&cnt4[rr], 1);
                    if (pos < KMAX) { cl[rr][pos] = c; w1l[rr][pos] = dw1; w2l[rr][pos] = dw2; }
                }
            }
        }
    }
    __syncthreads();
    int npv[RPB];
    for (int rr = 0; rr < RPB; ++rr) {
        int n  = cnt4[rr] < KMAX ? cnt4[rr] : KMAX;
        int np = (n + CH - 1) / CH * CH;
        npv[rr] = np;
        for (int i = n + t; i < np; i += 128) { cl[rr][i] = 0; w1l[rr][i] = 0.f; w2l[rr][i] = 0.f; }
    }
    __syncthreads();
    const int e2 = t >> 1, hf = t & 1;
    for (int rr = 0; rr < RPB; ++rr) {
        float acc = 0.f;
        for (int e0 = 0; e0 < npv[rr]; e0 += CH) {
            int c = cl[rr][e0 + e2];
            float* dst = &hj[e2][hf*64];
            if (SB) {
                const uint4* sv = (const uint4*)(s16 + (size_t)c*HID + hf*64);
                #pragma unroll
                for (int i = 0; i < 8; ++i) {
                    uint4 v = sv[i];
                    dst[8*i+0] = __uint_as_float(v.x << 16); dst[8*i+1] = __uint_as_float(v.x & 0xffff0000u);
                    dst[8*i+2] = __uint_as_float(v.y << 16); dst[8*i+3] = __uint_as_float(v.y & 0xffff0000u);
                    dst[8*i+4] = __uint_as_float(v.z << 16); dst[8*i+5] = __uint_as_float(v.z & 0xffff0000u);
                    dst[8*i+6] = __uint_as_float(v.w << 16); dst[8*i+7] = __uint_as_float(v.w & 0xffff0000u);
                }
            } else {
                const float4* sv = (const float4*)(s32 + (size_t)c*HID + hf*64);
                #pragma unroll
                for (int i = 0; i < 16; ++i) {
                    float4 v = sv[i];
                    dst[4*i+0] = v.x; dst[4*i+1] = v.y; dst[4*i+2] = v.z; dst[4*i+3] = v.w;
                }
            }
            __syncthreads();
            {
                const float* ha = &hs4[rr][hf*64];
                const float* hb = &hj[e2][hf*64];
                float p = 0.f;
                #pragma unroll
                for (int i = 0; i < 64; ++i) p = fmaf(ha[i], hb[i], p);
                p += __shfl_xor(p, 1);
                if (hf == 0) pl[e2] = fmaf(w1l[rr][e0+e2], fmaxf(p, 0.f), w2l[rr][e0+e2]);
            }
            __syncthreads();
            #pragma unroll
            for (int i = 0; i < CH; ++i) acc = fmaf(pl[i], hj[i][t], acc);
            __syncthreads();
        }
        ms[rr][t] = acc;
    }
    __syncthreads();
    {
        float bb = bu1[t];
        float a0 = bb, a1 = bb, a2 = bb, a3 = bb;
        for (int k = 0; k < HID; k += 4) {
            float w0 = Wu1[(k+0)*HID + t], w1 = Wu1[(k+1)*HID + t];
            float w2 = Wu1[(k+2)*HID + t], w3 = Wu1[(k+3)*HID + t];
            float4 c0 = *(const float4*)&hs4[0][k];
            float4 c1 = *(const float4*)&hs4[1][k];
            float4 c2 = *(const float4*)&hs4[2][k];
            float4 c3 = *(const float4*)&hs4[3][k];
            a0 = fmaf(c0.x,w0,a0); a0 = fmaf(c0.y,w1,a0); a0 = fmaf(c0.z,w2,a0); a0 = fmaf(c0.w,w3,a0);
            a1 = fmaf(c1.x,w0,a1); a1 = fmaf(c1.y,w1,a1); a1 = fmaf(c1.z,w2,a1); a1 = fmaf(c1.w,w3,a1);
            a2 = fmaf(c2.x,w0,a2); a2 = fmaf(c2.y,w1,a2); a2 = fmaf(c2.z,w2,a2); a2 = fmaf(c2.w,w3,a2);
            a3 = fmaf(c3.x,w0,a3); a3 = fmaf(c3.y,w1,a3); a3 = fmaf(c3.z,w2,a3); a3 = fmaf(c3.w,w3,a3);
        }
        for (int k = 0; k < HID; k += 4) {
            float w0 = Wu1[(HID+k+0)*HID + t], w1 = Wu1[(HID+k+1)*HID + t];
            float w2 = Wu1[(HID+k+2)*HID + t], w3 = Wu1[(HID+k+3)*HID + t];
            float4 c0 = *(const float4*)&ms[0][k];
            float4 c1 = *(const float4*)&ms[1][k];
            float4 c2 = *(const float4*)&ms[2][k];
            float4 c3 = *(const float4*)&ms[3][k];
            a0 = fmaf(c0.x,w0,a0); a0 = fmaf(c0.y,w1,a0); a0 = fmaf(c0.z,w2,a0); a0 = fmaf(c0.w,w3,a0);
            a1 = fmaf(c1.x,w0,a1); a1 = fmaf(c1.y,w1,a1); a1 = fmaf(c1.z,w2,a1); a1 = fmaf(c1.w,w3,a1);
            a2 = fmaf(c2.x,w0,a2); a2 = fmaf(c2.y,w1,a2); a2 = fmaf(c2.z,w2,a2); a2 = fmaf(c2.w,w3,a2);
            a3 = fmaf(c3.x,w0,a3); a3 = fmaf(c3.y,w1,a3); a3 = fmaf(c3.z,w2,a3); a3 = fmaf(c3.w,w3,a3);
        }
        h1s[0][t] = fmaxf(a0,0.f); h1s[1][t] = fmaxf(a1,0.f);
        h1s[2][t] = fmaxf(a2,0.f); h1s[3][t] = fmaxf(a3,0.f);
    }
    __syncthreads();
    {
        float bb = bu2[t];
        float b0 = bb, b1 = bb, b2 = bb, b3 = bb;
        for (int k = 0; k < HID; k += 4) {
            float w0 = Wu2[(k+0)*HID + t], w1 = Wu2[(k+1)*HID + t];
            float w2 = Wu2[(k+2)*HID + t], w3 = Wu2[(k+3)*HID + t];
            float4 c0 = *(const float4*)&h1s[0][k];
            float4 c1 = *(const float4*)&h1s[1][k];
            float4 c2 = *(const float4*)&h1s[2][k];
            float4 c3 = *(const float4*)&h1s[3][k];
            b0 = fmaf(c0.x,w0,b0); b0 = fmaf(c0.y,w1,b0); b0 = fmaf(c0.z,w2,b0); b0 = fmaf(c0.w,w3,b0);
            b1 = fmaf(c1.x,w0,b1); b1 = fmaf(c1.y,w1,b1); b1 = fmaf(c1.z,w2,b1); b1 = fmaf(c1.w,w3,b1);
            b2 = fmaf(c2.x,w0,b2); b2 = fmaf(c2.y,w1,b2); b2 = fmaf(c2.z,w2,b2); b2 = fmaf(c2.w,w3,b2);
            b3 = fmaf(c3.x,w0,b3); b3 = fmaf(c3.y,w1,b3); b3 = fmaf(c3.z,w2,b3); b3 = fmaf(c3.w,w3,b3);
        }
        hn[0][t] = hs4[0][t] + b0; hn[1][t] = hs4[1][t] + b1;
        hn[2][t] = hs4[2][t] + b2; hn[3][t] = hs4[3][t] + b3;
    }
    __syncthreads();
    {
        const int lr = t >> 5, j = t & 31;
        float s = 0.f;
        #pragma unroll
        for (int q = 0; q < 4; ++q) s += hn[lr][j + 32*q];
        #pragma unroll
        for (int k2 = 16; k2 >= 1; k2 >>= 1) s += __shfl_xor(s, k2);
        float mu = s * (1.0f/128.0f);
        float v = 0.f;
        #pragma unroll
        for (int q = 0; q < 4; ++q) { float z = hn[lr][j + 32*q] - mu; v = fmaf(z, z, v); }
        #pragma unroll
        for (int k2 = 16; k2 >= 1; k2 >>= 1) v += __shfl_xor(v, k2);
        float rstd = rsqrtf(v * (1.0f/128.0f) + 1e-5f);
        #pragma unroll
        for (int q = 0; q < 4; ++q) {
            int dd = j + 32*q;
            float val = fmaf((hn[lr][dd] - mu) * rstd, gam[dd], bet[dd]);
            if (DB) ((u16*)hdst)[(size_t)(r0+lr)*HID + dd] = f2b(val);
            else    ((float*)hdst)[(size_t)(r0+lr)*HID + dd] = val;
        }
    }
}

extern "C" void kernel_launch(void* const* d_in, const int* in_sizes, int n_in,
                              void* d_out, int out_size, void* d_ws, size_t ws_size,
                              hipStream_t stream)
{
    const float* x    = (const float*)d_in[0];
    const float* adj  = (const float*)d_in[1];
    const float* dist = (const float*)d_in[2];
    const float* Win  = (const float*)d_in[3];
    const float* bin  = (const float*)d_in[4];
    const float* Wu1  = (const float*)d_in[7];
    const float* bu1  = (const float*)d_in[8];
    const float* Wu2  = (const float*)d_in[9];
    const float* bu2  = (const float*)d_in[10];
    const float* gam  = (const float*)d_in[11];
    const float* bet  = (const float*)d_in[12];

    const size_t ebytes = (size_t)NN * KE * sizeof(float4);        // 10.49 MB
    const size_t nbytes = ((size_t)NN * sizeof(int) + 255) & ~255; // 16 KB
    const size_t hb32   = (size_t)NN * HID * sizeof(float);        // 2 MB
    const size_t need   = ebytes + nbytes + hb32;                  // ~12.5 MB

    if (ws_size >= need) {
        float4* edges = (float4*)d_ws;
        int*    nnzp  = (int*)((char*)d_ws + ebytes);
        float*  hA    = (float*)((char*)d_ws + ebytes + nbytes);
        float*  hB    = (float*)d_out;   // ping-pong partner; final result lands here

        k_build<<<NN, 256, 0, stream>>>(adj, dist, edges, nnzp);
        k_h0<false><<<NN, 128, 0, stream>>>(x, Win, bin, hA);
        k_fstep<<<NN/RPB, 256, 0, stream>>>(edges, nnzp, hA, Wu1, bu1, Wu2, bu2, gam, bet, hB);
        k_fstep<<<NN/RPB, 256, 0, stream>>>(edges, nnzp, hB, Wu1, bu1, Wu2, bu2, gam, bet, hA);
        k_fstep<<<NN/RPB, 256, 0, stream>>>(edges, nnzp, hA, Wu1, bu1, Wu2, bu2, gam, bet, hB);
    } else if (ws_size >= hb32) {
        void* A = d_ws; void* B = d_out;
        k_h0<false><<<NN, 128, 0, stream>>>(x, Win, bin, A);
        k_step<false,false><<<NN/RPB, 128, 0, stream>>>(adj, dist, A, B, Wu1, bu1, Wu2, bu2, gam, bet);
        k_step<false,false><<<NN/RPB, 128, 0, stream>>>(adj, dist, B, A, Wu1, bu1, Wu2, bu2, gam, bet);
        k_step<false,false><<<NN/RPB, 128, 0, stream>>>(adj, dist, A, B, Wu1, bu1, Wu2, bu2, gam, bet);
    } else {
        void* A = d_ws; void* B = d_out;
        k_h0<true><<<NN, 128, 0, stream>>>(x, Win, bin, A);
        k_step<true,true ><<<NN/RPB, 128, 0, stream>>>(adj, dist, A, B, Wu1, bu1, Wu2, bu2, gam, bet);
        k_step<true,true ><<<NN/RPB, 128, 0, stream>>>(adj, dist, B, A, Wu1, bu1, Wu2, bu2, gam, bet);
        k_step<true,false><<<NN/RPB, 128, 0, stream>>>(adj, dist, A, d_out, Wu1, bu1, Wu2, bu2, gam, bet);
    }
}